// Round 6
// baseline (450.640 us; speedup 1.0000x reference)
//
#include <hip/hip_runtime.h>

// WarmStartSinkhornLinear on MI355X — round 6.
// Scaling-form Sinkhorn + 256x256 bf16 MFMA GEMM.
// Round-6 changes:
//  (a) GEMM: ONE phase per K-tile (2 barriers instead of 4): register-prefetch
//      next tile's lo-frags + same-tile hi-frags before the barrier, 32 MFMA
//      after. vmcnt(4) once per K-tile. 4-buffer LDS ring, conflict-free
//      chunk-XOR swizzle f(row)=(row>>1)&3.
//  (b) recip_mv: 2 waves per row (grid 2048) for latency hiding.

#define L2E 1.44269504088896340736f

typedef __attribute__((ext_vector_type(8))) short bf16x8;
typedef __attribute__((ext_vector_type(4))) float f32x4;

__device__ __forceinline__ unsigned short f2bf(float x) {
  unsigned u = __float_as_uint(x);
  u += 0x7fffu + ((u >> 16) & 1u);  // RNE
  return (unsigned short)(u >> 16);
}
__device__ __forceinline__ float bf2f(short x) {
  return __uint_as_float(((unsigned)(unsigned short)x) << 16);
}

// ---- E[row,:] = bf16(exp(10*W[row,:] - rowmax)); one block per row.
__global__ void prep_e(const float* __restrict__ W, unsigned short* __restrict__ E) {
  const int row = blockIdx.x;
  const int t = threadIdx.x;
  const float* wp = W + ((size_t)row << 12);
  float v[16];
  float m = -3.4e38f;
#pragma unroll
  for (int ch = 0; ch < 4; ++ch) {
    float4 wv = *(const float4*)(wp + ch * 1024 + t * 4);
    float a0 = 10.f * wv.x, a1 = 10.f * wv.y, a2 = 10.f * wv.z, a3 = 10.f * wv.w;
    v[ch * 4 + 0] = a0; v[ch * 4 + 1] = a1; v[ch * 4 + 2] = a2; v[ch * 4 + 3] = a3;
    m = fmaxf(m, fmaxf(fmaxf(a0, a1), fmaxf(a2, a3)));
  }
#pragma unroll
  for (int off = 32; off > 0; off >>= 1) m = fmaxf(m, __shfl_xor(m, off));
  __shared__ float sm[4];
  if ((t & 63) == 0) sm[t >> 6] = m;
  __syncthreads();
  m = fmaxf(fmaxf(sm[0], sm[1]), fmaxf(sm[2], sm[3]));
  unsigned short* ep = E + ((size_t)row << 12);
#pragma unroll
  for (int ch = 0; ch < 4; ++ch) {
    ushort4 o;
    o.x = f2bf(exp2f((v[ch * 4 + 0] - m) * L2E));
    o.y = f2bf(exp2f((v[ch * 4 + 1] - m) * L2E));
    o.z = f2bf(exp2f((v[ch * 4 + 2] - m) * L2E));
    o.w = f2bf(exp2f((v[ch * 4 + 3] - m) * L2E));
    *(ushort4*)(ep + ch * 1024 + t * 4) = o;
  }
}

// ---- ET[j][i] = E[i][j]; 64x64 bf16 tiles via LDS.
__global__ void transpose_bf(const unsigned short* __restrict__ E,
                             unsigned short* __restrict__ ET) {
  __shared__ unsigned short tile[64][66];
  const int t = threadIdx.x;
  const int r = t >> 3;
  const int c8 = (t & 7) << 3;
  const size_t i0 = (size_t)blockIdx.y << 6;
  const size_t j0 = (size_t)blockIdx.x << 6;
#pragma unroll
  for (int h = 0; h < 2; ++h) {
    bf16x8 vv = *(const bf16x8*)(E + (i0 + h * 32 + r) * 4096 + j0 + c8);
#pragma unroll
    for (int e = 0; e < 8; ++e) tile[h * 32 + r][c8 + e] = (unsigned short)vv[e];
  }
  __syncthreads();
#pragma unroll
  for (int h = 0; h < 2; ++h) {
    bf16x8 vv;
#pragma unroll
    for (int e = 0; e < 8; ++e) vv[e] = (short)tile[c8 + e][h * 32 + r];
    *(bf16x8*)(ET + (j0 + h * 32 + r) * 4096 + i0 + c8) = vv;
  }
}

// ---- u[i] = exp(c_prev[i])
__global__ void init_u(const float* __restrict__ c_prev, float* __restrict__ u) {
  const int i = blockIdx.x * 256 + threadIdx.x;
  u[i] = exp2f(c_prev[i] * L2E);
}

// ---- out[row] = 1 / sum_j M[row][j]*uin[j]; 2 waves per row, 2 rows/block.
__global__ void recip_mv(const unsigned short* __restrict__ M,
                         const float* __restrict__ uin, float* __restrict__ vout) {
  const int t = threadIdx.x;
  const int l = t & 63, w = t >> 6;          // 4 waves
  const int row = (blockIdx.x << 1) + (w >> 1);
  const int half = (w & 1) << 11;            // j-offset 0 or 2048
  const unsigned short* mp = M + ((size_t)row << 12) + half;
  const float* up = uin + half;
  float s = 0.f;
#pragma unroll
  for (int ch = 0; ch < 4; ++ch) {
    const int j = (ch << 9) + (l << 3);
    bf16x8 e = *(const bf16x8*)(mp + j);
    const float4 u0 = *(const float4*)(up + j);
    const float4 u1 = *(const float4*)(up + j + 4);
    s = fmaf(bf2f(e[0]), u0.x, s);
    s = fmaf(bf2f(e[1]), u0.y, s);
    s = fmaf(bf2f(e[2]), u0.z, s);
    s = fmaf(bf2f(e[3]), u0.w, s);
    s = fmaf(bf2f(e[4]), u1.x, s);
    s = fmaf(bf2f(e[5]), u1.y, s);
    s = fmaf(bf2f(e[6]), u1.z, s);
    s = fmaf(bf2f(e[7]), u1.w, s);
  }
#pragma unroll
  for (int off = 32; off > 0; off >>= 1) s += __shfl_xor(s, off);
  __shared__ float sm[4];
  if (l == 0) sm[w] = s;
  __syncthreads();
  if (t < 2) vout[(blockIdx.x << 1) + t] = 1.f / (sm[t << 1] + sm[(t << 1) + 1]);
}

// ---- xb[t,j] = bf16(x[t,j] * u[j])
__global__ void scale_x(const float* __restrict__ X, const float* __restrict__ u,
                        unsigned short* __restrict__ Y) {
  const size_t idx = ((size_t)blockIdx.x * 256 + threadIdx.x) * 4;
  const int col = (int)(idx & 4095);
  float4 xv = *(const float4*)(X + idx);
  float4 uu = *(const float4*)(u + col);
  ushort4 o;
  o.x = f2bf(xv.x * uu.x);
  o.y = f2bf(xv.y * uu.y);
  o.z = f2bf(xv.z * uu.z);
  o.w = f2bf(xv.w * uu.w);
  *(ushort4*)(Y + idx) = o;
}

// ---- C[m,n] = v[n] * sum_k A[m,k]*B[n,k]; A [8192,4096], B [4096,4096] bf16.
// 256x256 tile, BK=32, 8 waves (2Mx4N), 4-buffer LDS ring, ONE phase/K-tile:
//   read hiA(p) + lo-frags(p+1) | stage A,B(p+3) | vmcnt(4) | barrier |
//   16 MFMA lo(p) + 16 MFMA hi(p) | barrier
// Invariants: tile p+1 LDS-resident at phase p (phase p-1's vmcnt(4)+barrier);
// stage target buf (p+3)&3 = (p-1)&3 is dead (tile p-1's last ds_read completed
// before phase p-1's end barrier via lgkmcnt-before-MFMA).
__global__ __launch_bounds__(512, 2) void gemm_bt(const unsigned short* __restrict__ A,
                                                  const unsigned short* __restrict__ B,
                                                  const float* __restrict__ vscale,
                                                  float* __restrict__ C) {
  __shared__ unsigned short lds[65536];  // 128 KB
  const int t = threadIdx.x;
  const int l = t & 63;
  const int w = t >> 6;          // 0..7
  const int wm = w >> 2, wn = w & 3;

  // XCD-bijective swizzle (512 % 8 == 0) + GROUP_M=4
  int pid = blockIdx.x;
  pid = (pid & 7) * 64 + (pid >> 3);
  const int grp = pid >> 6;
  const int rem = pid & 63;
  const int bm = (grp << 2) + (rem & 3);
  const int bn = rem >> 2;
  const int m0 = bm << 8;
  const int n0 = bn << 8;

  // staging: thread t writes LDS row (t>>2), physical chunk (t&3); fetch the
  // logical chunk that belongs there: logical = (t&3) ^ f(row), f(r)=(r>>1)&3.
  const int ca = (((t & 3) ^ ((t >> 3) & 3)) << 3);
  const unsigned short* gA = A + (size_t)(m0 + (t >> 2)) * 4096 + ca;
  const unsigned short* gB = B + (size_t)(n0 + (t >> 2)) * 4096 + ca;

  // ds_read: lane l, logical chunk (l>>4) of row (l&15) -> physical =
  // (l>>4) ^ ((l>>1)&3). Conflict-free: each 8-lane octet covers all 32 banks.
  const int xc = (((l >> 4) ^ ((l >> 1) & 3)) << 3);
  const int aOff = (wm * 128 + (l & 15)) * 32 + xc;
  const int bOff = (wn * 64 + (l & 15)) * 32 + xc;

  auto stageA = [&](int kt) {
    const int b = kt & 3;
    const unsigned short* g = gA + (size_t)kt * 32;
#pragma unroll
    for (int ra = 0; ra < 2; ++ra)
      __builtin_amdgcn_global_load_lds(
          (const __attribute__((address_space(1))) void*)(g + (size_t)ra * 524288),
          (__attribute__((address_space(3))) void*)((char*)lds + b * 16384 + ra * 8192 + w * 1024),
          16, 0, 0);
  };
  auto stageB = [&](int kt) {
    const int b = kt & 3;
    const unsigned short* g = gB + (size_t)kt * 32;
#pragma unroll
    for (int ra = 0; ra < 2; ++ra)
      __builtin_amdgcn_global_load_lds(
          (const __attribute__((address_space(1))) void*)(g + (size_t)ra * 524288),
          (__attribute__((address_space(3))) void*)((char*)lds + 65536 + b * 16384 + ra * 8192 + w * 1024),
          16, 0, 0);
  };

  f32x4 acc[8][4] = {};

  // Prologue: stage K-tiles 0..2 (12 loads); vmcnt(4) -> tiles 0,1 landed.
  stageA(0); stageB(0);
  stageA(1); stageB(1);
  stageA(2); stageB(2);
  asm volatile("s_waitcnt vmcnt(4)" ::: "memory");
  __builtin_amdgcn_s_barrier();

  bf16x8 cA[4], cB[4], nA[4], nB[4], hiA[4];
#pragma unroll
  for (int i = 0; i < 4; ++i) cA[i] = *(const bf16x8*)(lds + aOff + i * 512);
#pragma unroll
  for (int j = 0; j < 4; ++j) cB[j] = *(const bf16x8*)(lds + 32768 + bOff + j * 512);

#define PHASE(KT, CLA, CLB, NLA, NLB)                                             \
  {                                                                               \
    const int kt_ = (KT);                                                         \
    const unsigned short* aL = lds + (kt_ & 3) * 8192 + aOff;                     \
    _Pragma("unroll")                                                             \
    for (int i = 0; i < 4; ++i) hiA[i] = *(const bf16x8*)(aL + (4 + i) * 512);    \
    if (kt_ <= 126) {                                                             \
      const unsigned short* aN = lds + ((kt_ + 1) & 3) * 8192 + aOff;             \
      const unsigned short* bN = lds + 32768 + ((kt_ + 1) & 3) * 8192 + bOff;     \
      _Pragma("unroll")                                                           \
      for (int i = 0; i < 4; ++i) NLA[i] = *(const bf16x8*)(aN + i * 512);        \
      _Pragma("unroll")                                                           \
      for (int j = 0; j < 4; ++j) NLB[j] = *(const bf16x8*)(bN + j * 512);        \
    }                                                                             \
    if (kt_ <= 124) { stageA(kt_ + 3); stageB(kt_ + 3); }                         \
    if (kt_ <= 124)      asm volatile("s_waitcnt vmcnt(4)" ::: "memory");         \
    else if (kt_ == 125) asm volatile("s_waitcnt vmcnt(0)" ::: "memory");         \
    __builtin_amdgcn_sched_barrier(0);                                            \
    __builtin_amdgcn_s_barrier();                                                 \
    __builtin_amdgcn_s_setprio(1);                                                \
    _Pragma("unroll")                                                             \
    for (int i = 0; i < 4; ++i)                                                   \
      _Pragma("unroll")                                                           \
      for (int j = 0; j < 4; ++j)                                                 \
        acc[i][j] = __builtin_amdgcn_mfma_f32_16x16x32_bf16(CLA[i], CLB[j],       \
                                                            acc[i][j], 0, 0, 0); \
    _Pragma("unroll")                                                             \
    for (int i = 0; i < 4; ++i)                                                   \
      _Pragma("unroll")                                                           \
      for (int j = 0; j < 4; ++j)                                                 \
        acc[4 + i][j] = __builtin_amdgcn_mfma_f32_16x16x32_bf16(hiA[i], CLB[j],   \
                                                                acc[4 + i][j],   \
                                                                0, 0, 0);         \
    __builtin_amdgcn_s_setprio(0);                                                \
    __builtin_amdgcn_s_barrier();                                                 \
  }

  for (int kt = 0; kt < 128; kt += 2) {
    PHASE(kt, cA, cB, nA, nB)
    PHASE(kt + 1, nA, nB, cA, cB)
  }
#undef PHASE

  // Epilogue: C[m,n] = acc * v[n]
  const int crow = (l >> 4) << 2;
  const int ccol = l & 15;
#pragma unroll
  for (int j = 0; j < 4; ++j) {
    const int colj = n0 + (wn << 6) + (j << 4) + ccol;
    const float vs = vscale[colj];
#pragma unroll
    for (int i = 0; i < 8; ++i) {
      const int rowi = m0 + (wm << 7) + (i << 4) + crow;
#pragma unroll
      for (int q = 0; q < 4; ++q)
        C[((size_t)(rowi + q) << 12) + colj] = acc[i][j][q] * vs;
    }
  }
}

extern "C" void kernel_launch(void* const* d_in, const int* in_sizes, int n_in,
                              void* d_out, int out_size, void* d_ws, size_t ws_size,
                              hipStream_t stream) {
  const float* x      = (const float*)d_in[0];   // [4,2048,4096] f32
  const float* weight = (const float*)d_in[1];   // [4096,4096] f32
  const float* c_prev = (const float*)d_in[3];   // [1,4096] f32; r_prev unused
  float* out = (float*)d_out;

  char* ws = (char*)d_ws;
  float* u = (float*)ws;                                   // 4096 f32
  float* v = (float*)(ws + (16 << 10));                    // 4096 f32
  unsigned short* E  = (unsigned short*)(ws + (64 << 10)); // 33.5 MB
  unsigned short* ET = E + (size_t)4096 * 4096;            // 33.5 MB (dead after iters)
  unsigned short* xb = ET;                                 // xb overlays ET (67 MB)

  prep_e<<<4096, 256, 0, stream>>>(weight, E);
  transpose_bf<<<dim3(64, 64), 256, 0, stream>>>(E, ET);
  init_u<<<16, 256, 0, stream>>>(c_prev, u);

  for (int it = 0; it < 10; ++it) {
    recip_mv<<<2048, 256, 0, stream>>>(E, u, v);   // v = 1/(E u)
    recip_mv<<<2048, 256, 0, stream>>>(ET, v, u);  // u = 1/(E^T v)
  }

  scale_x<<<32768, 256, 0, stream>>>(x, u, xb);    // xb = bf16(x * u), kills ET

  gemm_bt<<<512, 512, 0, stream>>>(xb, E, v, out);
}

// Round 7
// 436.369 us; speedup vs baseline: 1.0327x; 1.0327x over previous
//
#include <hip/hip_runtime.h>

// WarmStartSinkhornLinear on MI355X — round 7.
// Scaling-form Sinkhorn + 256x256 bf16 MFMA GEMM, m201-style 8-phase schedule:
// BK=64 as two k-halves of 32; LDS ring of 4 A-slots + 4 B-slots (256x32 each,
// 128 KB total); each phase = {8|4 ds_read_b128, stage one half (2 gload_lds),
// barrier, lgkmcnt(0), 16 MFMA, [vmcnt(4)], barrier}. Counted vmcnt (never 0
// until tail). Conflict-free chunk-XOR swizzle phys = c ^ ((row>>1)&3).

#define L2E 1.44269504088896340736f

typedef __attribute__((ext_vector_type(8))) short bf16x8;
typedef __attribute__((ext_vector_type(4))) float f32x4;

__device__ __forceinline__ unsigned short f2bf(float x) {
  unsigned u = __float_as_uint(x);
  u += 0x7fffu + ((u >> 16) & 1u);  // RNE
  return (unsigned short)(u >> 16);
}
__device__ __forceinline__ float bf2f(short x) {
  return __uint_as_float(((unsigned)(unsigned short)x) << 16);
}

// ---- E[row,:] = bf16(exp(10*W[row,:] - rowmax)); one block per row.
__global__ void prep_e(const float* __restrict__ W, unsigned short* __restrict__ E) {
  const int row = blockIdx.x;
  const int t = threadIdx.x;
  const float* wp = W + ((size_t)row << 12);
  float v[16];
  float m = -3.4e38f;
#pragma unroll
  for (int ch = 0; ch < 4; ++ch) {
    float4 wv = *(const float4*)(wp + ch * 1024 + t * 4);
    float a0 = 10.f * wv.x, a1 = 10.f * wv.y, a2 = 10.f * wv.z, a3 = 10.f * wv.w;
    v[ch * 4 + 0] = a0; v[ch * 4 + 1] = a1; v[ch * 4 + 2] = a2; v[ch * 4 + 3] = a3;
    m = fmaxf(m, fmaxf(fmaxf(a0, a1), fmaxf(a2, a3)));
  }
#pragma unroll
  for (int off = 32; off > 0; off >>= 1) m = fmaxf(m, __shfl_xor(m, off));
  __shared__ float sm[4];
  if ((t & 63) == 0) sm[t >> 6] = m;
  __syncthreads();
  m = fmaxf(fmaxf(sm[0], sm[1]), fmaxf(sm[2], sm[3]));
  unsigned short* ep = E + ((size_t)row << 12);
#pragma unroll
  for (int ch = 0; ch < 4; ++ch) {
    ushort4 o;
    o.x = f2bf(exp2f((v[ch * 4 + 0] - m) * L2E));
    o.y = f2bf(exp2f((v[ch * 4 + 1] - m) * L2E));
    o.z = f2bf(exp2f((v[ch * 4 + 2] - m) * L2E));
    o.w = f2bf(exp2f((v[ch * 4 + 3] - m) * L2E));
    *(ushort4*)(ep + ch * 1024 + t * 4) = o;
  }
}

// ---- ET[j][i] = E[i][j]; 64x64 bf16 tiles via LDS.
__global__ void transpose_bf(const unsigned short* __restrict__ E,
                             unsigned short* __restrict__ ET) {
  __shared__ unsigned short tile[64][66];
  const int t = threadIdx.x;
  const int r = t >> 3;
  const int c8 = (t & 7) << 3;
  const size_t i0 = (size_t)blockIdx.y << 6;
  const size_t j0 = (size_t)blockIdx.x << 6;
#pragma unroll
  for (int h = 0; h < 2; ++h) {
    bf16x8 vv = *(const bf16x8*)(E + (i0 + h * 32 + r) * 4096 + j0 + c8);
#pragma unroll
    for (int e = 0; e < 8; ++e) tile[h * 32 + r][c8 + e] = (unsigned short)vv[e];
  }
  __syncthreads();
#pragma unroll
  for (int h = 0; h < 2; ++h) {
    bf16x8 vv;
#pragma unroll
    for (int e = 0; e < 8; ++e) vv[e] = (short)tile[c8 + e][h * 32 + r];
    *(bf16x8*)(ET + (j0 + h * 32 + r) * 4096 + i0 + c8) = vv;
  }
}

// ---- u[i] = exp(c_prev[i])
__global__ void init_u(const float* __restrict__ c_prev, float* __restrict__ u) {
  const int i = blockIdx.x * 256 + threadIdx.x;
  u[i] = exp2f(c_prev[i] * L2E);
}

// ---- out[row] = 1 / sum_j M[row][j]*uin[j]; 1 wave per row, 4 rows/block.
__global__ void recip_mv(const unsigned short* __restrict__ M,
                         const float* __restrict__ uin, float* __restrict__ vout) {
  const int t = threadIdx.x;
  const int l = t & 63, w = t >> 6;
  const int row = (blockIdx.x << 2) + w;
  const unsigned short* mp = M + ((size_t)row << 12);
  float s = 0.f;
#pragma unroll
  for (int ch = 0; ch < 8; ++ch) {
    const int j = (ch << 9) + (l << 3);
    bf16x8 e = *(const bf16x8*)(mp + j);
    const float4 u0 = *(const float4*)(uin + j);
    const float4 u1 = *(const float4*)(uin + j + 4);
    s = fmaf(bf2f(e[0]), u0.x, s);
    s = fmaf(bf2f(e[1]), u0.y, s);
    s = fmaf(bf2f(e[2]), u0.z, s);
    s = fmaf(bf2f(e[3]), u0.w, s);
    s = fmaf(bf2f(e[4]), u1.x, s);
    s = fmaf(bf2f(e[5]), u1.y, s);
    s = fmaf(bf2f(e[6]), u1.z, s);
    s = fmaf(bf2f(e[7]), u1.w, s);
  }
#pragma unroll
  for (int off = 32; off > 0; off >>= 1) s += __shfl_xor(s, off);
  if (l == 0) vout[row] = 1.f / s;
}

// ---- xb[t,j] = bf16(x[t,j] * u[j])
__global__ void scale_x(const float* __restrict__ X, const float* __restrict__ u,
                        unsigned short* __restrict__ Y) {
  const size_t idx = ((size_t)blockIdx.x * 256 + threadIdx.x) * 4;
  const int col = (int)(idx & 4095);
  float4 xv = *(const float4*)(X + idx);
  float4 uu = *(const float4*)(u + col);
  ushort4 o;
  o.x = f2bf(xv.x * uu.x);
  o.y = f2bf(xv.y * uu.y);
  o.z = f2bf(xv.z * uu.z);
  o.w = f2bf(xv.w * uu.w);
  *(ushort4*)(Y + idx) = o;
}

// ---- C[m,n] = v[n] * sum_k A[m,k]*B[n,k]; A [8192,4096], B [4096,4096] bf16.
// 256x256 tile, 8 waves (2Mx4N), per-wave output 128x64.
// k-half h = 32 K-elems; slot = h&3. A slots @ [s*8192) hw, B @ [32768+s*8192).
// Slot layout [256 rows][32 k], phys 8-hw chunk = c ^ ((row>>1)&3).
// Phase (kh,mh): read 4 A-frags (+4 B-frags if mh==0) of slot (2kt+kh);
//   stage one half (2 gload_lds); barrier; lgkmcnt(0); 16 MFMA; [vmcnt]; barrier.
// Stage schedule: ph(0,0):A(2kt+2) ph(0,1):B(2kt+2) ph(1,0):A(2kt+3) ph(1,1):B(2kt+3).
// Waits: end ph(0,1): vmcnt(4) (half 2kt+1 landed; 2kt+2's 4 loads in flight);
//        end ph(1,1): vmcnt(4) (half 2kt+2 landed; 2kt+3's in flight). Tail kt=63: 0/none.
__global__ __launch_bounds__(512, 2) void gemm_bt(const unsigned short* __restrict__ A,
                                                  const unsigned short* __restrict__ B,
                                                  const float* __restrict__ vscale,
                                                  float* __restrict__ C) {
  __shared__ unsigned short lds[65536];  // 128 KB
  const int t = threadIdx.x;
  const int l = t & 63;
  const int w = t >> 6;          // 0..7
  const int wm = w >> 2, wn = w & 3;

  // XCD-bijective swizzle (512 % 8 == 0) + GROUP_M=4
  int pid = blockIdx.x;
  pid = (pid & 7) * 64 + (pid >> 3);
  const int grp = pid >> 6;
  const int rem = pid & 63;
  const int bm = (grp << 2) + (rem & 3);
  const int bn = rem >> 2;
  const int m0 = bm << 8;
  const int n0 = bn << 8;

  // staging: thread t -> slot byte t*16: row t>>2, phys chunk t&3; fetch logical
  // chunk (t&3) ^ f(row), f(r)=(r>>1)&3 -> (t>>3)&3 (same for both 128-row halves).
  const int ca = (((t & 3) ^ ((t >> 3) & 3)) << 3);
  const unsigned short* gA = A + (size_t)(m0 + (t >> 2)) * 4096 + ca;
  const unsigned short* gB = B + (size_t)(n0 + (t >> 2)) * 4096 + ca;

  // ds_read: lane l wants logical chunk (l>>4) of row (l&15): phys =
  // (l>>4) ^ ((l>>1)&3). Each 8-lane octet covers all 32 banks exactly once.
  const int xc = (((l >> 4) ^ ((l >> 1) & 3)) << 3);
  const int aOff = wm * 4096 + (l & 15) * 32 + xc;  // + mh*2048 + i*512
  const int bOff = wn * 2048 + (l & 15) * 32 + xc;  // + j*512

  auto stage = [&](const unsigned short* gbase, int h, int isB) {
    const int slot = h & 3;
    const unsigned short* g = gbase + (size_t)h * 32;
#pragma unroll
    for (int ra = 0; ra < 2; ++ra)
      __builtin_amdgcn_global_load_lds(
          (const __attribute__((address_space(1))) void*)(g + (size_t)ra * 524288),
          (__attribute__((address_space(3))) void*)((char*)lds + isB * 65536 + slot * 16384 + ra * 8192 + w * 1024),
          16, 0, 0);
  };

  f32x4 acc[8][4] = {};
  bf16x8 afr[4], bfr[4];

  // Prologue: stage halves 0,1 (A,B each = 8 loads); wait half 0 (4 in flight).
  stage(gA, 0, 0); stage(gB, 0, 1);
  stage(gA, 1, 0); stage(gB, 1, 1);
  asm volatile("s_waitcnt vmcnt(4)" ::: "memory");
  __builtin_amdgcn_s_barrier();

#define PHASE(SLOT, MH, STAGE_STMT, WAIT_STMT)                                     \
  {                                                                                \
    const unsigned short* aL = lds + (SLOT) * 8192 + aOff + (MH) * 2048;           \
    _Pragma("unroll")                                                              \
    for (int i = 0; i < 4; ++i) afr[i] = *(const bf16x8*)(aL + i * 512);           \
    if ((MH) == 0) {                                                               \
      const unsigned short* bL = lds + 32768 + (SLOT) * 8192 + bOff;               \
      _Pragma("unroll")                                                            \
      for (int j = 0; j < 4; ++j) bfr[j] = *(const bf16x8*)(bL + j * 512);         \
    }                                                                              \
    STAGE_STMT;                                                                    \
    __builtin_amdgcn_s_barrier();                                                  \
    asm volatile("s_waitcnt lgkmcnt(0)" ::: "memory");                             \
    __builtin_amdgcn_sched_barrier(0);                                             \
    __builtin_amdgcn_s_setprio(1);                                                 \
    _Pragma("unroll")                                                              \
    for (int i = 0; i < 4; ++i)                                                    \
      _Pragma("unroll")                                                            \
      for (int j = 0; j < 4; ++j)                                                  \
        acc[(MH) * 4 + i][j] = __builtin_amdgcn_mfma_f32_16x16x32_bf16(            \
            afr[i], bfr[j], acc[(MH) * 4 + i][j], 0, 0, 0);                        \
    __builtin_amdgcn_s_setprio(0);                                                 \
    WAIT_STMT;                                                                     \
    __builtin_amdgcn_s_barrier();                                                  \
  }

  for (int kt = 0; kt < 64; kt += 2) {
    // ktu = kt (even): consume slots 0,1 (halves 2kt,2kt+1); stage halves 2kt+2,2kt+3.
    PHASE(0, 0, { if (kt <= 62) stage(gA, 2 * kt + 2, 0); }, {})
    PHASE(0, 1, { if (kt <= 62) stage(gB, 2 * kt + 2, 1); },
          { if (kt <= 62) asm volatile("s_waitcnt vmcnt(4)" ::: "memory");
            else          asm volatile("s_waitcnt vmcnt(0)" ::: "memory"); })
    PHASE(1, 0, { if (kt <= 62) stage(gA, 2 * kt + 3, 0); }, {})
    PHASE(1, 1, { if (kt <= 62) stage(gB, 2 * kt + 3, 1); },
          { if (kt <= 62) asm volatile("s_waitcnt vmcnt(4)" ::: "memory"); })
    // ktu = kt+1 (odd): consume slots 2,3 (halves 2kt+2,2kt+3); stage 2kt+4,2kt+5.
    PHASE(2, 0, { if (kt + 1 <= 62) stage(gA, 2 * kt + 4, 0); }, {})
    PHASE(2, 1, { if (kt + 1 <= 62) stage(gB, 2 * kt + 4, 1); },
          { if (kt + 1 <= 62) asm volatile("s_waitcnt vmcnt(4)" ::: "memory");
            else              asm volatile("s_waitcnt vmcnt(0)" ::: "memory"); })
    PHASE(3, 0, { if (kt + 1 <= 62) stage(gA, 2 * kt + 5, 0); }, {})
    PHASE(3, 1, { if (kt + 1 <= 62) stage(gB, 2 * kt + 5, 1); },
          { if (kt + 1 <= 62) asm volatile("s_waitcnt vmcnt(4)" ::: "memory"); })
  }
#undef PHASE

  // Epilogue: C[m,n] = acc * v[n]
  const int crow = (l >> 4) << 2;
  const int ccol = l & 15;
#pragma unroll
  for (int j = 0; j < 4; ++j) {
    const int colj = n0 + (wn << 6) + (j << 4) + ccol;
    const float vs = vscale[colj];
#pragma unroll
    for (int i = 0; i < 8; ++i) {
      const int rowi = m0 + (wm << 7) + (i << 4) + crow;
#pragma unroll
      for (int q = 0; q < 4; ++q)
        C[((size_t)(rowi + q) << 12) + colj] = acc[i][j][q] * vs;
    }
  }
}

extern "C" void kernel_launch(void* const* d_in, const int* in_sizes, int n_in,
                              void* d_out, int out_size, void* d_ws, size_t ws_size,
                              hipStream_t stream) {
  const float* x      = (const float*)d_in[0];   // [4,2048,4096] f32
  const float* weight = (const float*)d_in[1];   // [4096,4096] f32
  const float* c_prev = (const float*)d_in[3];   // [1,4096] f32; r_prev unused
  float* out = (float*)d_out;

  char* ws = (char*)d_ws;
  float* u = (float*)ws;                                   // 4096 f32
  float* v = (float*)(ws + (16 << 10));                    // 4096 f32
  unsigned short* E  = (unsigned short*)(ws + (64 << 10)); // 33.5 MB
  unsigned short* ET = E + (size_t)4096 * 4096;            // 33.5 MB (dead after iters)
  unsigned short* xb = ET;                                 // xb overlays ET (67 MB)

  prep_e<<<4096, 256, 0, stream>>>(weight, E);
  transpose_bf<<<dim3(64, 64), 256, 0, stream>>>(E, ET);
  init_u<<<16, 256, 0, stream>>>(c_prev, u);

  for (int it = 0; it < 10; ++it) {
    recip_mv<<<1024, 256, 0, stream>>>(E, u, v);   // v = 1/(E u)
    recip_mv<<<1024, 256, 0, stream>>>(ET, v, u);  // u = 1/(E^T v)
  }

  scale_x<<<32768, 256, 0, stream>>>(x, u, xb);    // xb = bf16(x * u), kills ET

  gemm_bt<<<512, 512, 0, stream>>>(xb, E, v, out);
}